// Round 10
// baseline (663.305 us; speedup 1.0000x reference)
//
#include <hip/hip_runtime.h>
#include <hip/hip_bf16.h>

// MoE Experts v10: BOTH GEMMs on the proven deep-pipelined 256x256 K_PIPE
// (3-buf LDS, counted vmcnt(4), involution swizzle, setprio). g2 epilogue =
// weighted atomic scatter (<=8 adders/elem with kc=4 K-split), dc-innermost
// task order for H L2 reuse. g1 unchanged from v9 (measured ~206us).

#define T_TOK   8192
#define D_MODEL 1024
#define D_FF    4096
#define NE      8
#define MT2     72                 // 256-row tiles
#define MT_MAX  (MT2 * 2)
#define ROWS_MAX (MT2 * 256)       // 18432
#define BUFB    32768
#define LDS_G1  98304

typedef float f32x4 __attribute__((ext_vector_type(4)));
typedef short s16x8 __attribute__((ext_vector_type(8)));
typedef short s16x4 __attribute__((ext_vector_type(4)));
typedef unsigned short u16;

__device__ __forceinline__ u16 f2bf(float x) {
  __hip_bfloat16 h = __float2bfloat16(x);   // RNE
  return *reinterpret_cast<u16*>(&h);
}

__device__ __forceinline__ s16x8 cvt8(float4 a, float4 b) {
  s16x8 v;
  v[0] = (short)f2bf(a.x); v[1] = (short)f2bf(a.y);
  v[2] = (short)f2bf(a.z); v[3] = (short)f2bf(a.w);
  v[4] = (short)f2bf(b.x); v[5] = (short)f2bf(b.y);
  v[6] = (short)f2bf(b.z); v[7] = (short)f2bf(b.w);
  return v;
}

__device__ __forceinline__ void gload_lds16(const void* g, void* l) {
  __builtin_amdgcn_global_load_lds((const __attribute__((address_space(1))) void*)g,
                                   (__attribute__((address_space(3))) void*)l,
                                   16, 0, 0);
}

// ---------------- routing compaction ----------------
__global__ void moe_route(const int* __restrict__ sel, const float* __restrict__ rw,
                          int* __restrict__ cnt, int* __restrict__ tidx,
                          float* __restrict__ tw) {
  int t = blockIdx.x * blockDim.x + threadIdx.x;
  if (t >= T_TOK) return;
  int e0 = 0, e1 = 0;
  #pragma unroll
  for (int e = 0; e < NE; ++e) {
    if (sel[t * 16 + e])     e0 = e;
    if (sel[t * 16 + 8 + e]) e1 = e;
  }
  float w0 = rw[2 * t], w1 = rw[2 * t + 1];
  if (e0 == e1) {
    int p = atomicAdd(&cnt[e0], 1);
    tidx[e0 * T_TOK + p] = t; tw[e0 * T_TOK + p] = w0 + w1;
  } else {
    int p = atomicAdd(&cnt[e0], 1);
    tidx[e0 * T_TOK + p] = t; tw[e0 * T_TOK + p] = w0;
    int q = atomicAdd(&cnt[e1], 1);
    tidx[e1 * T_TOK + q] = t; tw[e1 * T_TOK + q] = w1;
  }
}

// ---------------- tile map: 256-aligned per-expert segments ----------------
__global__ void moe_tilemap(const int* __restrict__ cnt, const int* __restrict__ tidx,
                            const float* __restrict__ tw, int* __restrict__ te256,
                            int* __restrict__ tokr, float* __restrict__ wr) {
  int off[NE + 1];
  {
    int o = 0;
    #pragma unroll
    for (int e = 0; e < NE; ++e) { off[e] = o; o += (cnt[e] + 255) & ~255; }
    off[NE] = o;
  }
  const int total = off[NE];
  const int gid = blockIdx.x * blockDim.x + threadIdx.x;
  const int stride = gridDim.x * blockDim.x;
  for (int t = gid; t < MT2; t += stride) {
    int r0 = t * 256; int e = -1;
    if (r0 < total) {
      #pragma unroll
      for (int i = NE - 1; i >= 0; --i) if (r0 >= off[i]) { e = i; break; }
    }
    te256[t] = e;
  }
  for (int i = gid; i < ROWS_MAX; i += stride) {
    if (i >= total) { tokr[i] = -1; wr[i] = 0.f; continue; }
    int e = 0;
    #pragma unroll
    for (int k = NE - 1; k >= 0; --k) if (i >= off[k]) { e = k; break; }
    int j = i - off[e];
    int ok = j < cnt[e];
    tokr[i] = ok ? tidx[e * T_TOK + j] : -1;
    wr[i]   = ok ? tw[e * T_TOK + j] : 0.f;
  }
}

// ---------------- gather X rows -> bf16 Xg ----------------
__global__ void moe_gather_x(const float* __restrict__ hs, const int* __restrict__ tokr,
                             u16* __restrict__ Xg) {
  int row = blockIdx.x;
  int tok = tokr[row];
  int c = threadIdx.x * 4;
  u16* dst = Xg + (size_t)row * D_MODEL + c;
  s16x4 o;
  if (tok < 0) {
    o[0] = o[1] = o[2] = o[3] = 0;
  } else {
    float4 v = *(const float4*)(hs + (size_t)tok * D_MODEL + c);
    o[0] = (short)f2bf(v.x); o[1] = (short)f2bf(v.y);
    o[2] = (short)f2bf(v.z); o[3] = (short)f2bf(v.w);
  }
  *(s16x4*)dst = o;
}

// ---------------- f32 -> bf16 weight converts ----------------
__global__ void moe_cvt_w(const float* __restrict__ wi, const float* __restrict__ wo,
                          u16* __restrict__ wib, u16* __restrict__ wob) {
  const size_t NW = (size_t)NE * D_FF * D_MODEL;
  size_t i = ((size_t)blockIdx.x * blockDim.x + threadIdx.x) * 8;
  const float* src; u16* dst;
  if (i < NW) { src = wi + i; dst = wib + i; }
  else        { src = wo + (i - NW); dst = wob + (i - NW); }
  float4 a = *(const float4*)(src);
  float4 b = *(const float4*)(src + 4);
  *(s16x8*)dst = cvt8(a, b);
}

__global__ void moe_cvt_wi_s(const float* __restrict__ wi, u16* __restrict__ wis,
                             int W, int f0) {
  size_t i = ((size_t)blockIdx.x * blockDim.x + threadIdx.x) * 8;
  size_t per = (size_t)W * D_MODEL;
  int e = (int)(i / per); size_t r = i % per;
  const float* src = wi + ((size_t)e * D_FF + f0) * D_MODEL + r;
  float4 a = *(const float4*)src;
  float4 b = *(const float4*)(src + 4);
  *(s16x8*)(wis + i) = cvt8(a, b);
}

__global__ void moe_cvt_wo_s(const float* __restrict__ wo, u16* __restrict__ wos,
                             int W, int f0) {
  size_t i = ((size_t)blockIdx.x * blockDim.x + threadIdx.x) * 8;
  size_t per = (size_t)D_MODEL * W;
  int e = (int)(i / per); size_t r = i % per;
  int row = (int)(r / W), col = (int)(r % W);
  const float* src = wo + ((size_t)e * D_MODEL + row) * D_FF + f0 + col;
  float4 a = *(const float4*)src;
  float4 b = *(const float4*)(src + 4);
  *(s16x8*)(wos + i) = cvt8(a, b);
}

// ================= proven deep-pipelined K loop (v9) =================
// acc[8][4] per thread; la/lb fragment reads use the involution-corrected
// inner offset; stage uses pre-swizzled global source -> linear LDS dest.
#define K_PIPE_BODY(NT_, PITCH_A, PITCH_B)                                        \
  auto stage = [&](int kb, char* lbuf) {                                          \
    _Pragma("unroll")                                                             \
    for (int j = 0; j < 2; ++j)                                                   \
      gload_lds16(gA + (size_t)(j * 128 + srow) * (PITCH_A) + kb + scol,          \
                  lbuf + j * 8192 + tid * 16);                                    \
    _Pragma("unroll")                                                             \
    for (int j = 0; j < 2; ++j)                                                   \
      gload_lds16(gB + (size_t)(j * 128 + srow) * (PITCH_B) + kb + scol,          \
                  lbuf + 16384 + j * 8192 + tid * 16);                            \
  };                                                                              \
  stage(0, lds);                                                                  \
  stage(64, lds + BUFB);                                                          \
  int bufi = 0;                                                                   \
  for (int t = 0; t < (NT_); ++t) {                                               \
    if (t < (NT_) - 1) { asm volatile("s_waitcnt vmcnt(4)" ::: "memory"); }       \
    else               { asm volatile("s_waitcnt vmcnt(0)" ::: "memory"); }       \
    asm volatile("s_barrier" ::: "memory");                                       \
    const char* la = lds + bufi * BUFB + wm * 8192;                               \
    const char* lb = lds + bufi * BUFB + 16384 + wn * 4096;                       \
    if (t + 2 < (NT_)) {                                                          \
      int b2 = bufi + 2; if (b2 >= 3) b2 -= 3;                                    \
      stage((t + 2) * 64, lds + b2 * BUFB);                                       \
    }                                                                             \
    s16x8 bq0 = *(const s16x8*)(lb + 0 * 1024 + inner);                           \
    s16x8 bq1 = *(const s16x8*)(lb + 1 * 1024 + inner);                           \
    s16x8 bq2 = *(const s16x8*)(lb + 2 * 1024 + inner);                           \
    s16x8 bq3 = *(const s16x8*)(lb + 3 * 1024 + inner);                           \
    {                                                                             \
      s16x8 a0 = *(const s16x8*)(la + 0 * 1024 + inner);                          \
      s16x8 a1 = *(const s16x8*)(la + 1 * 1024 + inner);                          \
      s16x8 a2 = *(const s16x8*)(la + 2 * 1024 + inner);                          \
      s16x8 a3 = *(const s16x8*)(la + 3 * 1024 + inner);                          \
      __builtin_amdgcn_s_setprio(1);                                              \
      acc[0][0] = __builtin_amdgcn_mfma_f32_16x16x32_bf16(a0, bq0, acc[0][0], 0, 0, 0); \
      acc[0][1] = __builtin_amdgcn_mfma_f32_16x16x32_bf16(a0, bq1, acc[0][1], 0, 0, 0); \
      acc[0][2] = __builtin_amdgcn_mfma_f32_16x16x32_bf16(a0, bq2, acc[0][2], 0, 0, 0); \
      acc[0][3] = __builtin_amdgcn_mfma_f32_16x16x32_bf16(a0, bq3, acc[0][3], 0, 0, 0); \
      acc[1][0] = __builtin_amdgcn_mfma_f32_16x16x32_bf16(a1, bq0, acc[1][0], 0, 0, 0); \
      acc[1][1] = __builtin_amdgcn_mfma_f32_16x16x32_bf16(a1, bq1, acc[1][1], 0, 0, 0); \
      acc[1][2] = __builtin_amdgcn_mfma_f32_16x16x32_bf16(a1, bq2, acc[1][2], 0, 0, 0); \
      acc[1][3] = __builtin_amdgcn_mfma_f32_16x16x32_bf16(a1, bq3, acc[1][3], 0, 0, 0); \
      acc[2][0] = __builtin_amdgcn_mfma_f32_16x16x32_bf16(a2, bq0, acc[2][0], 0, 0, 0); \
      acc[2][1] = __builtin_amdgcn_mfma_f32_16x16x32_bf16(a2, bq1, acc[2][1], 0, 0, 0); \
      acc[2][2] = __builtin_amdgcn_mfma_f32_16x16x32_bf16(a2, bq2, acc[2][2], 0, 0, 0); \
      acc[2][3] = __builtin_amdgcn_mfma_f32_16x16x32_bf16(a2, bq3, acc[2][3], 0, 0, 0); \
      acc[3][0] = __builtin_amdgcn_mfma_f32_16x16x32_bf16(a3, bq0, acc[3][0], 0, 0, 0); \
      acc[3][1] = __builtin_amdgcn_mfma_f32_16x16x32_bf16(a3, bq1, acc[3][1], 0, 0, 0); \
      acc[3][2] = __builtin_amdgcn_mfma_f32_16x16x32_bf16(a3, bq2, acc[3][2], 0, 0, 0); \
      acc[3][3] = __builtin_amdgcn_mfma_f32_16x16x32_bf16(a3, bq3, acc[3][3], 0, 0, 0); \
      __builtin_amdgcn_s_setprio(0);                                              \
    }                                                                             \
    __builtin_amdgcn_s_barrier();                                                 \
    {                                                                             \
      s16x8 a0 = *(const s16x8*)(la + 4 * 1024 + inner);                          \
      s16x8 a1 = *(const s16x8*)(la + 5 * 1024 + inner);                          \
      s16x8 a2 = *(const s16x8*)(la + 6 * 1024 + inner);                          \
      s16x8 a3 = *(const s16x8*)(la + 7 * 1024 + inner);                          \
      __builtin_amdgcn_s_setprio(1);                                              \
      acc[4][0] = __builtin_amdgcn_mfma_f32_16x16x32_bf16(a0, bq0, acc[4][0], 0, 0, 0); \
      acc[4][1] = __builtin_amdgcn_mfma_f32_16x16x32_bf16(a0, bq1, acc[4][1], 0, 0, 0); \
      acc[4][2] = __builtin_amdgcn_mfma_f32_16x16x32_bf16(a0, bq2, acc[4][2], 0, 0, 0); \
      acc[4][3] = __builtin_amdgcn_mfma_f32_16x16x32_bf16(a0, bq3, acc[4][3], 0, 0, 0); \
      acc[5][0] = __builtin_amdgcn_mfma_f32_16x16x32_bf16(a1, bq0, acc[5][0], 0, 0, 0); \
      acc[5][1] = __builtin_amdgcn_mfma_f32_16x16x32_bf16(a1, bq1, acc[5][1], 0, 0, 0); \
      acc[5][2] = __builtin_amdgcn_mfma_f32_16x16x32_bf16(a1, bq2, acc[5][2], 0, 0, 0); \
      acc[5][3] = __builtin_amdgcn_mfma_f32_16x16x32_bf16(a1, bq3, acc[5][3], 0, 0, 0); \
      acc[6][0] = __builtin_amdgcn_mfma_f32_16x16x32_bf16(a2, bq0, acc[6][0], 0, 0, 0); \
      acc[6][1] = __builtin_amdgcn_mfma_f32_16x16x32_bf16(a2, bq1, acc[6][1], 0, 0, 0); \
      acc[6][2] = __builtin_amdgcn_mfma_f32_16x16x32_bf16(a2, bq2, acc[6][2], 0, 0, 0); \
      acc[6][3] = __builtin_amdgcn_mfma_f32_16x16x32_bf16(a2, bq3, acc[6][3], 0, 0, 0); \
      acc[7][0] = __builtin_amdgcn_mfma_f32_16x16x32_bf16(a3, bq0, acc[7][0], 0, 0, 0); \
      acc[7][1] = __builtin_amdgcn_mfma_f32_16x16x32_bf16(a3, bq1, acc[7][1], 0, 0, 0); \
      acc[7][2] = __builtin_amdgcn_mfma_f32_16x16x32_bf16(a3, bq2, acc[7][2], 0, 0, 0); \
      acc[7][3] = __builtin_amdgcn_mfma_f32_16x16x32_bf16(a3, bq3, acc[7][3], 0, 0, 0); \
      __builtin_amdgcn_s_setprio(0);                                              \
    }                                                                             \
    bufi += 1; if (bufi >= 3) bufi -= 3;                                          \
  }

// ---------------- GEMM1 (v9 proven): H = relu(Xg @ Wi^T) ----------------
template <bool FULL>
__global__ __launch_bounds__(512, 1)
void moe_g1(const u16* __restrict__ Xg, const u16* __restrict__ wiP,
            const int* __restrict__ te256, u16* __restrict__ H,
            int W, int f0) {
  extern __shared__ char lds[];
  const int GR = gridDim.x;
  const int task = (blockIdx.x & 7) * (GR >> 3) + (blockIdx.x >> 3);
  const int mt = task % MT2;
  const int nc = task / MT2;
  const int e = te256[mt];
  if (e < 0) return;
  const int grow0 = mt * 256;
  const int fcol = nc * 256;

  const int tid = threadIdx.x;
  const int lane = tid & 63, wv = tid >> 6;
  const int lg = lane >> 4, ll = lane & 15;
  const int wm = wv >> 2, wn = wv & 3;

  const int sw = (tid * 16) ^ (((tid >> 3) & 7) << 4);
  const int srow = sw >> 6, scol = sw & 63;
  const int inner = (ll * 64 + lg * 16) ^ (((ll >> 1) & 7) << 4);

  const char* gA = (const char*)(Xg + (size_t)grow0 * D_MODEL);
  const char* gB = (const char*)(wiP + (FULL ? ((size_t)e * D_FF + f0 + fcol)
                                             : ((size_t)e * W + fcol)) * D_MODEL);

  f32x4 acc[8][4];
  #pragma unroll
  for (int m = 0; m < 8; ++m)
    #pragma unroll
    for (int n = 0; n < 4; ++n) acc[m][n] = (f32x4){0.f, 0.f, 0.f, 0.f};

  const int NT = D_MODEL / 32;
  K_PIPE_BODY(NT, 2048, 2048)

  #pragma unroll
  for (int mf = 0; mf < 8; ++mf) {
    #pragma unroll
    for (int r = 0; r < 4; ++r) {
      int row = grow0 + wm * 128 + mf * 16 + lg * 4 + r;
      u16* hp = H + (size_t)row * W + fcol + wn * 64 + ll;
      #pragma unroll
      for (int nf = 0; nf < 4; ++nf) {
        float v = acc[mf][nf][r];
        hp[nf * 16] = f2bf(v > 0.f ? v : 0.f);
      }
    }
  }
}

// ---------------- GEMM2 (deep-piped): out += w .* (H @ Wo^T) ----------------
// task = dc + 4*(mt + MT2*kc): dc innermost (4 readers of one H chunk adjacent
// on one XCD). Block: rows 256 x dcol 256, K-chunk KCH. Epilogue: atomic f32.
template <bool FULL>
__global__ __launch_bounds__(512, 1)
void moe_g2(const u16* __restrict__ H, const u16* __restrict__ woP,
            const int* __restrict__ te256, const int* __restrict__ tokr,
            const float* __restrict__ wr, float* __restrict__ out,
            int W, int f0, int KCH) {
  extern __shared__ char lds[];
  const int GR = gridDim.x;
  const int task = (blockIdx.x & 7) * (GR >> 3) + (blockIdx.x >> 3);
  const int dc = task & 3;
  const int rest = task >> 2;
  const int mt = rest % MT2;
  const int kc = rest / MT2;
  const int e = te256[mt];
  if (e < 0) return;
  const int grow0 = mt * 256;
  const int dcol0 = dc * 256;

  const int tid = threadIdx.x;
  const int lane = tid & 63, wv = tid >> 6;
  const int lg = lane >> 4, ll = lane & 15;
  const int wm = wv >> 2, wn = wv & 3;

  const int sw = (tid * 16) ^ (((tid >> 3) & 7) << 4);
  const int srow = sw >> 6, scol = sw & 63;
  const int inner = (ll * 64 + lg * 16) ^ (((ll >> 1) & 7) << 4);

  const size_t pA = (size_t)W * 2;                      // H row pitch (bytes)
  const size_t pB = (FULL ? (size_t)D_FF : (size_t)W) * 2;  // Wo row pitch
  const char* gA = (const char*)(H + (size_t)grow0 * W + (size_t)kc * KCH);
  const char* gB = (const char*)(woP + ((size_t)e * D_MODEL + dcol0) * (pB / 2)
                                 + (FULL ? f0 : 0) + (size_t)kc * KCH);

  f32x4 acc[8][4];
  #pragma unroll
  for (int m = 0; m < 8; ++m)
    #pragma unroll
    for (int n = 0; n < 4; ++n) acc[m][n] = (f32x4){0.f, 0.f, 0.f, 0.f};

  const int NT = KCH / 32;
  K_PIPE_BODY(NT, pA, pB)

  // epilogue: same (row,col) mapping as g1; weighted atomic scatter to out.
  #pragma unroll
  for (int mf = 0; mf < 8; ++mf) {
    #pragma unroll
    for (int r = 0; r < 4; ++r) {
      int row = grow0 + wm * 128 + mf * 16 + lg * 4 + r;
      int tok = tokr[row];
      if (tok >= 0) {
        float w = wr[row];
        float* op = out + (size_t)tok * D_MODEL + dcol0 + wn * 64 + ll;
        #pragma unroll
        for (int nf = 0; nf < 4; ++nf)
          atomicAdd(op + nf * 16, acc[mf][nf][r] * w);
      }
    }
  }
}

// ---------------- host ----------------
extern "C" void kernel_launch(void* const* d_in, const int* in_sizes, int n_in,
                              void* d_out, int out_size, void* d_ws, size_t ws_size,
                              hipStream_t stream) {
  const float* hs  = (const float*)d_in[0];
  const int*   sel = (const int*)d_in[1];
  const float* rw  = (const float*)d_in[2];
  const float* wi  = (const float*)d_in[3];
  const float* wo  = (const float*)d_in[4];
  float* out = (float*)d_out;

  const size_t NW   = (size_t)NE * D_FF * D_MODEL;
  const size_t CTRL = 1u << 20;
  const size_t WB   = 2 * NW * sizeof(u16);            // 128 MiB
  const size_t XGB  = (size_t)ROWS_MAX * D_MODEL * 2;  // 37.7 MiB

  // ---- config ladder ----
  bool FULLW = true; int W = D_FF;
  {
    bool found = false;
    for (int f : {1, 2, 4, 8, 16}) {
      int Wc = D_FF / f;
      size_t need = CTRL + WB + XGB + (size_t)ROWS_MAX * Wc * 2;
      if (need <= ws_size) { FULLW = true; W = Wc; found = true; break; }
    }
    if (!found) {
      for (int Wc : {1024, 512, 256}) {
        size_t sl = (size_t)2 * NE * Wc * D_MODEL * 2;
        size_t need = CTRL + sl + XGB + (size_t)ROWS_MAX * Wc * 2;
        if (need <= ws_size) { FULLW = false; W = Wc; break; }
      }
    }
  }
  const int FS = D_FF / W;

  // ---- ws layout ----
  size_t off = 0;
  auto take = [&](size_t b) -> char* {
    char* r = (char*)d_ws + off; off = (off + b + 255) & ~(size_t)255; return r;
  };
  int*   tidx = (int*)take((size_t)NE * T_TOK * 4);
  float* tw   = (float*)take((size_t)NE * T_TOK * 4);
  int*   tokr = (int*)take((size_t)ROWS_MAX * 4);
  float* wrr  = (float*)take((size_t)ROWS_MAX * 4);
  int*   te2  = (int*)take(MT2 * 4);
  int*   cnt  = (int*)take(256);
  off = CTRL;
  u16 *wiP, *woP;
  if (FULLW) { wiP = (u16*)take(NW * 2); woP = (u16*)take(NW * 2); }
  else       { wiP = (u16*)take((size_t)NE * W * D_MODEL * 2);
               woP = (u16*)take((size_t)NE * D_MODEL * W * 2); }
  u16* Xg   = (u16*)take(XGB);
  u16* Hbuf = (u16*)take((size_t)ROWS_MAX * W * 2);

  // ---- routing / staging ----
  hipMemsetAsync(cnt, 0, 256, stream);
  hipMemsetAsync(d_out, 0, (size_t)out_size * sizeof(float), stream);
  moe_route<<<T_TOK / 256, 256, 0, stream>>>(sel, rw, cnt, tidx, tw);
  moe_tilemap<<<64, 256, 0, stream>>>(cnt, tidx, tw, te2, tokr, wrr);
  moe_gather_x<<<ROWS_MAX, 256, 0, stream>>>(hs, tokr, Xg);
  if (FULLW)
    moe_cvt_w<<<(int)(2 * NW / 8 / 256), 256, 0, stream>>>(wi, wo, wiP, woP);

  hipFuncSetAttribute(reinterpret_cast<const void*>(&moe_g1<true>),
                      hipFuncAttributeMaxDynamicSharedMemorySize, LDS_G1);
  hipFuncSetAttribute(reinterpret_cast<const void*>(&moe_g1<false>),
                      hipFuncAttributeMaxDynamicSharedMemorySize, LDS_G1);
  hipFuncSetAttribute(reinterpret_cast<const void*>(&moe_g2<true>),
                      hipFuncAttributeMaxDynamicSharedMemorySize, LDS_G1);
  hipFuncSetAttribute(reinterpret_cast<const void*>(&moe_g2<false>),
                      hipFuncAttributeMaxDynamicSharedMemorySize, LDS_G1);

  // ---- GEMM passes ----
  const int KCH = (W >= 1024) ? 1024 : W;
  const int g1grid = MT2 * (W / 256);                 // 1152 at FS=1
  const int g2grid = MT2 * 4 * (W / KCH);             // 1152 at FS=1
  const int cvtblk = (int)(((size_t)NE * W * D_MODEL / 8) / 256);

  for (int p = 0; p < FS; ++p) {
    const int f0 = p * W;
    if (!FULLW) {
      moe_cvt_wi_s<<<cvtblk, 256, 0, stream>>>(wi, wiP, W, f0);
      moe_cvt_wo_s<<<cvtblk, 256, 0, stream>>>(wo, woP, W, f0);
    }
    if (FULLW) {
      moe_g1<true><<<g1grid, 512, LDS_G1, stream>>>(Xg, wiP, te2, Hbuf, W, f0);
      moe_g2<true><<<g2grid, 512, LDS_G1, stream>>>(Hbuf, woP, te2, tokr, wrr,
                                                    out, W, f0, KCH);
    } else {
      moe_g1<false><<<g1grid, 512, LDS_G1, stream>>>(Xg, wiP, te2, Hbuf, W, f0);
      moe_g2<false><<<g2grid, 512, LDS_G1, stream>>>(Hbuf, woP, te2, tokr, wrr,
                                                     out, W, f0, KCH);
    }
  }
}

// Round 11
// 537.148 us; speedup vs baseline: 1.2349x; 1.2349x over previous
//
#include <hip/hip_runtime.h>
#include <hip/hip_bf16.h>

// MoE Experts v11: g1 = v9 deep-pipe 256x256 (proven, ~206us). g2 = deep-pipe
// re-geometried 256x128 tile: 24KB/buf x3 = 72KB LDS -> 2 blocks/CU (fixes
// v10's 19% occupancy), kc=2 K-split -> 64 atomics/thread (fixes atomic tail),
// vmcnt(3) counted boundary (3 loads/stage). dc-innermost task order.

#define T_TOK   8192
#define D_MODEL 1024
#define D_FF    4096
#define NE      8
#define MT2     72                 // 256-row tiles
#define ROWS_MAX (MT2 * 256)       // 18432
#define BUFB    32768              // g1 buffer stride (A16K+B16K)
#define LDS_G1  98304
#define BUF2    24576              // g2 buffer stride (A16K+B8K)
#define LDS_G2  73728

typedef float f32x4 __attribute__((ext_vector_type(4)));
typedef short s16x8 __attribute__((ext_vector_type(8)));
typedef short s16x4 __attribute__((ext_vector_type(4)));
typedef unsigned short u16;

__device__ __forceinline__ u16 f2bf(float x) {
  __hip_bfloat16 h = __float2bfloat16(x);   // RNE
  return *reinterpret_cast<u16*>(&h);
}

__device__ __forceinline__ s16x8 cvt8(float4 a, float4 b) {
  s16x8 v;
  v[0] = (short)f2bf(a.x); v[1] = (short)f2bf(a.y);
  v[2] = (short)f2bf(a.z); v[3] = (short)f2bf(a.w);
  v[4] = (short)f2bf(b.x); v[5] = (short)f2bf(b.y);
  v[6] = (short)f2bf(b.z); v[7] = (short)f2bf(b.w);
  return v;
}

__device__ __forceinline__ void gload_lds16(const void* g, void* l) {
  __builtin_amdgcn_global_load_lds((const __attribute__((address_space(1))) void*)g,
                                   (__attribute__((address_space(3))) void*)l,
                                   16, 0, 0);
}

// ---------------- routing compaction ----------------
__global__ void moe_route(const int* __restrict__ sel, const float* __restrict__ rw,
                          int* __restrict__ cnt, int* __restrict__ tidx,
                          float* __restrict__ tw) {
  int t = blockIdx.x * blockDim.x + threadIdx.x;
  if (t >= T_TOK) return;
  int e0 = 0, e1 = 0;
  #pragma unroll
  for (int e = 0; e < NE; ++e) {
    if (sel[t * 16 + e])     e0 = e;
    if (sel[t * 16 + 8 + e]) e1 = e;
  }
  float w0 = rw[2 * t], w1 = rw[2 * t + 1];
  if (e0 == e1) {
    int p = atomicAdd(&cnt[e0], 1);
    tidx[e0 * T_TOK + p] = t; tw[e0 * T_TOK + p] = w0 + w1;
  } else {
    int p = atomicAdd(&cnt[e0], 1);
    tidx[e0 * T_TOK + p] = t; tw[e0 * T_TOK + p] = w0;
    int q = atomicAdd(&cnt[e1], 1);
    tidx[e1 * T_TOK + q] = t; tw[e1 * T_TOK + q] = w1;
  }
}

// ---------------- tile map: 256-aligned per-expert segments ----------------
__global__ void moe_tilemap(const int* __restrict__ cnt, const int* __restrict__ tidx,
                            const float* __restrict__ tw, int* __restrict__ te256,
                            int* __restrict__ tokr, float* __restrict__ wr) {
  int off[NE + 1];
  {
    int o = 0;
    #pragma unroll
    for (int e = 0; e < NE; ++e) { off[e] = o; o += (cnt[e] + 255) & ~255; }
    off[NE] = o;
  }
  const int total = off[NE];
  const int gid = blockIdx.x * blockDim.x + threadIdx.x;
  const int stride = gridDim.x * blockDim.x;
  for (int t = gid; t < MT2; t += stride) {
    int r0 = t * 256; int e = -1;
    if (r0 < total) {
      #pragma unroll
      for (int i = NE - 1; i >= 0; --i) if (r0 >= off[i]) { e = i; break; }
    }
    te256[t] = e;
  }
  for (int i = gid; i < ROWS_MAX; i += stride) {
    if (i >= total) { tokr[i] = -1; wr[i] = 0.f; continue; }
    int e = 0;
    #pragma unroll
    for (int k = NE - 1; k >= 0; --k) if (i >= off[k]) { e = k; break; }
    int j = i - off[e];
    int ok = j < cnt[e];
    tokr[i] = ok ? tidx[e * T_TOK + j] : -1;
    wr[i]   = ok ? tw[e * T_TOK + j] : 0.f;
  }
}

// ---------------- gather X rows -> bf16 Xg ----------------
__global__ void moe_gather_x(const float* __restrict__ hs, const int* __restrict__ tokr,
                             u16* __restrict__ Xg) {
  int row = blockIdx.x;
  int tok = tokr[row];
  int c = threadIdx.x * 4;
  u16* dst = Xg + (size_t)row * D_MODEL + c;
  s16x4 o;
  if (tok < 0) {
    o[0] = o[1] = o[2] = o[3] = 0;
  } else {
    float4 v = *(const float4*)(hs + (size_t)tok * D_MODEL + c);
    o[0] = (short)f2bf(v.x); o[1] = (short)f2bf(v.y);
    o[2] = (short)f2bf(v.z); o[3] = (short)f2bf(v.w);
  }
  *(s16x4*)dst = o;
}

// ---------------- f32 -> bf16 weight converts ----------------
__global__ void moe_cvt_w(const float* __restrict__ wi, const float* __restrict__ wo,
                          u16* __restrict__ wib, u16* __restrict__ wob) {
  const size_t NW = (size_t)NE * D_FF * D_MODEL;
  size_t i = ((size_t)blockIdx.x * blockDim.x + threadIdx.x) * 8;
  const float* src; u16* dst;
  if (i < NW) { src = wi + i; dst = wib + i; }
  else        { src = wo + (i - NW); dst = wob + (i - NW); }
  float4 a = *(const float4*)(src);
  float4 b = *(const float4*)(src + 4);
  *(s16x8*)dst = cvt8(a, b);
}

__global__ void moe_cvt_wi_s(const float* __restrict__ wi, u16* __restrict__ wis,
                             int W, int f0) {
  size_t i = ((size_t)blockIdx.x * blockDim.x + threadIdx.x) * 8;
  size_t per = (size_t)W * D_MODEL;
  int e = (int)(i / per); size_t r = i % per;
  const float* src = wi + ((size_t)e * D_FF + f0) * D_MODEL + r;
  float4 a = *(const float4*)src;
  float4 b = *(const float4*)(src + 4);
  *(s16x8*)(wis + i) = cvt8(a, b);
}

__global__ void moe_cvt_wo_s(const float* __restrict__ wo, u16* __restrict__ wos,
                             int W, int f0) {
  size_t i = ((size_t)blockIdx.x * blockDim.x + threadIdx.x) * 8;
  size_t per = (size_t)D_MODEL * W;
  int e = (int)(i / per); size_t r = i % per;
  int row = (int)(r / W), col = (int)(r % W);
  const float* src = wo + ((size_t)e * D_MODEL + row) * D_FF + f0 + col;
  float4 a = *(const float4*)src;
  float4 b = *(const float4*)(src + 4);
  *(s16x8*)(wos + i) = cvt8(a, b);
}

// ---------------- GEMM1 (v9 proven, unchanged): H = relu(Xg @ Wi^T) ---------
template <bool FULL>
__global__ __launch_bounds__(512, 1)
void moe_g1(const u16* __restrict__ Xg, const u16* __restrict__ wiP,
            const int* __restrict__ te256, u16* __restrict__ H,
            int W, int f0) {
  extern __shared__ char lds[];
  const int GR = gridDim.x;
  const int task = (blockIdx.x & 7) * (GR >> 3) + (blockIdx.x >> 3);
  const int mt = task % MT2;
  const int nc = task / MT2;
  const int e = te256[mt];
  if (e < 0) return;
  const int grow0 = mt * 256;
  const int fcol = nc * 256;

  const int tid = threadIdx.x;
  const int lane = tid & 63, wv = tid >> 6;
  const int lg = lane >> 4, ll = lane & 15;
  const int wm = wv >> 2, wn = wv & 3;

  const int sw = (tid * 16) ^ (((tid >> 3) & 7) << 4);
  const int srow = sw >> 6, scol = sw & 63;
  const int inner = (ll * 64 + lg * 16) ^ (((ll >> 1) & 7) << 4);

  const char* gA = (const char*)(Xg + (size_t)grow0 * D_MODEL);
  const char* gB = (const char*)(wiP + (FULL ? ((size_t)e * D_FF + f0 + fcol)
                                             : ((size_t)e * W + fcol)) * D_MODEL);

  f32x4 acc[8][4];
  #pragma unroll
  for (int m = 0; m < 8; ++m)
    #pragma unroll
    for (int n = 0; n < 4; ++n) acc[m][n] = (f32x4){0.f, 0.f, 0.f, 0.f};

  auto stage = [&](int kb, char* lbuf) {
    #pragma unroll
    for (int j = 0; j < 2; ++j)
      gload_lds16(gA + (size_t)(j * 128 + srow) * 2048 + kb + scol,
                  lbuf + j * 8192 + tid * 16);
    #pragma unroll
    for (int j = 0; j < 2; ++j)
      gload_lds16(gB + (size_t)(j * 128 + srow) * 2048 + kb + scol,
                  lbuf + 16384 + j * 8192 + tid * 16);
  };

  const int NT = D_MODEL / 32;
  stage(0, lds);
  stage(64, lds + BUFB);
  int bufi = 0;
  for (int t = 0; t < NT; ++t) {
    if (t < NT - 1) { asm volatile("s_waitcnt vmcnt(4)" ::: "memory"); }
    else            { asm volatile("s_waitcnt vmcnt(0)" ::: "memory"); }
    asm volatile("s_barrier" ::: "memory");
    const char* la = lds + bufi * BUFB + wm * 8192;
    const char* lb = lds + bufi * BUFB + 16384 + wn * 4096;
    if (t + 2 < NT) {
      int b2 = bufi + 2; if (b2 >= 3) b2 -= 3;
      stage((t + 2) * 64, lds + b2 * BUFB);
    }
    s16x8 bq0 = *(const s16x8*)(lb + 0 * 1024 + inner);
    s16x8 bq1 = *(const s16x8*)(lb + 1 * 1024 + inner);
    s16x8 bq2 = *(const s16x8*)(lb + 2 * 1024 + inner);
    s16x8 bq3 = *(const s16x8*)(lb + 3 * 1024 + inner);
    {
      s16x8 a0 = *(const s16x8*)(la + 0 * 1024 + inner);
      s16x8 a1 = *(const s16x8*)(la + 1 * 1024 + inner);
      s16x8 a2 = *(const s16x8*)(la + 2 * 1024 + inner);
      s16x8 a3 = *(const s16x8*)(la + 3 * 1024 + inner);
      __builtin_amdgcn_s_setprio(1);
      acc[0][0] = __builtin_amdgcn_mfma_f32_16x16x32_bf16(a0, bq0, acc[0][0], 0, 0, 0);
      acc[0][1] = __builtin_amdgcn_mfma_f32_16x16x32_bf16(a0, bq1, acc[0][1], 0, 0, 0);
      acc[0][2] = __builtin_amdgcn_mfma_f32_16x16x32_bf16(a0, bq2, acc[0][2], 0, 0, 0);
      acc[0][3] = __builtin_amdgcn_mfma_f32_16x16x32_bf16(a0, bq3, acc[0][3], 0, 0, 0);
      acc[1][0] = __builtin_amdgcn_mfma_f32_16x16x32_bf16(a1, bq0, acc[1][0], 0, 0, 0);
      acc[1][1] = __builtin_amdgcn_mfma_f32_16x16x32_bf16(a1, bq1, acc[1][1], 0, 0, 0);
      acc[1][2] = __builtin_amdgcn_mfma_f32_16x16x32_bf16(a1, bq2, acc[1][2], 0, 0, 0);
      acc[1][3] = __builtin_amdgcn_mfma_f32_16x16x32_bf16(a1, bq3, acc[1][3], 0, 0, 0);
      acc[2][0] = __builtin_amdgcn_mfma_f32_16x16x32_bf16(a2, bq0, acc[2][0], 0, 0, 0);
      acc[2][1] = __builtin_amdgcn_mfma_f32_16x16x32_bf16(a2, bq1, acc[2][1], 0, 0, 0);
      acc[2][2] = __builtin_amdgcn_mfma_f32_16x16x32_bf16(a2, bq2, acc[2][2], 0, 0, 0);
      acc[2][3] = __builtin_amdgcn_mfma_f32_16x16x32_bf16(a2, bq3, acc[2][3], 0, 0, 0);
      acc[3][0] = __builtin_amdgcn_mfma_f32_16x16x32_bf16(a3, bq0, acc[3][0], 0, 0, 0);
      acc[3][1] = __builtin_amdgcn_mfma_f32_16x16x32_bf16(a3, bq1, acc[3][1], 0, 0, 0);
      acc[3][2] = __builtin_amdgcn_mfma_f32_16x16x32_bf16(a3, bq2, acc[3][2], 0, 0, 0);
      acc[3][3] = __builtin_amdgcn_mfma_f32_16x16x32_bf16(a3, bq3, acc[3][3], 0, 0, 0);
      __builtin_amdgcn_s_setprio(0);
    }
    __builtin_amdgcn_s_barrier();
    {
      s16x8 a0 = *(const s16x8*)(la + 4 * 1024 + inner);
      s16x8 a1 = *(const s16x8*)(la + 5 * 1024 + inner);
      s16x8 a2 = *(const s16x8*)(la + 6 * 1024 + inner);
      s16x8 a3 = *(const s16x8*)(la + 7 * 1024 + inner);
      __builtin_amdgcn_s_setprio(1);
      acc[4][0] = __builtin_amdgcn_mfma_f32_16x16x32_bf16(a0, bq0, acc[4][0], 0, 0, 0);
      acc[4][1] = __builtin_amdgcn_mfma_f32_16x16x32_bf16(a0, bq1, acc[4][1], 0, 0, 0);
      acc[4][2] = __builtin_amdgcn_mfma_f32_16x16x32_bf16(a0, bq2, acc[4][2], 0, 0, 0);
      acc[4][3] = __builtin_amdgcn_mfma_f32_16x16x32_bf16(a0, bq3, acc[4][3], 0, 0, 0);
      acc[5][0] = __builtin_amdgcn_mfma_f32_16x16x32_bf16(a1, bq0, acc[5][0], 0, 0, 0);
      acc[5][1] = __builtin_amdgcn_mfma_f32_16x16x32_bf16(a1, bq1, acc[5][1], 0, 0, 0);
      acc[5][2] = __builtin_amdgcn_mfma_f32_16x16x32_bf16(a1, bq2, acc[5][2], 0, 0, 0);
      acc[5][3] = __builtin_amdgcn_mfma_f32_16x16x32_bf16(a1, bq3, acc[5][3], 0, 0, 0);
      acc[6][0] = __builtin_amdgcn_mfma_f32_16x16x32_bf16(a2, bq0, acc[6][0], 0, 0, 0);
      acc[6][1] = __builtin_amdgcn_mfma_f32_16x16x32_bf16(a2, bq1, acc[6][1], 0, 0, 0);
      acc[6][2] = __builtin_amdgcn_mfma_f32_16x16x32_bf16(a2, bq2, acc[6][2], 0, 0, 0);
      acc[6][3] = __builtin_amdgcn_mfma_f32_16x16x32_bf16(a2, bq3, acc[6][3], 0, 0, 0);
      acc[7][0] = __builtin_amdgcn_mfma_f32_16x16x32_bf16(a3, bq0, acc[7][0], 0, 0, 0);
      acc[7][1] = __builtin_amdgcn_mfma_f32_16x16x32_bf16(a3, bq1, acc[7][1], 0, 0, 0);
      acc[7][2] = __builtin_amdgcn_mfma_f32_16x16x32_bf16(a3, bq2, acc[7][2], 0, 0, 0);
      acc[7][3] = __builtin_amdgcn_mfma_f32_16x16x32_bf16(a3, bq3, acc[7][3], 0, 0, 0);
      __builtin_amdgcn_s_setprio(0);
    }
    bufi += 1; if (bufi >= 3) bufi -= 3;
  }

  #pragma unroll
  for (int mf = 0; mf < 8; ++mf) {
    #pragma unroll
    for (int r = 0; r < 4; ++r) {
      int row = grow0 + wm * 128 + mf * 16 + lg * 4 + r;
      u16* hp = H + (size_t)row * W + fcol + wn * 64 + ll;
      #pragma unroll
      for (int nf = 0; nf < 4; ++nf) {
        float v = acc[mf][nf][r];
        hp[nf * 16] = f2bf(v > 0.f ? v : 0.f);
      }
    }
  }
}

// ---------------- GEMM2 (deep-pipe 256x128, 2 blocks/CU) --------------------
// task = dc + 8*(mt + MT2*kc); tile rows 256 x dcols 128, KCH=W/2 (kc in 0..1).
// 8 waves of 64x64 (wm=wv>>1 in 0..3, wn=wv&1). 3 LDS bufs of 24KB; stage =
// 2 A-loads + 1 B-load per thread -> counted vmcnt(3). Epilogue: 64 atomics.
template <bool FULL>
__global__ __launch_bounds__(512, 4)
void moe_g2(const u16* __restrict__ H, const u16* __restrict__ woP,
            const int* __restrict__ te256, const int* __restrict__ tokr,
            const float* __restrict__ wr, float* __restrict__ out,
            int W, int f0, int KCH) {
  extern __shared__ char lds[];
  const int GR = gridDim.x;
  const int task = (blockIdx.x & 7) * (GR >> 3) + (blockIdx.x >> 3);
  const int dc = task & 7;
  const int rest = task >> 3;
  const int mt = rest % MT2;
  const int kc = rest / MT2;
  const int e = te256[mt];
  if (e < 0) return;
  const int grow0 = mt * 256;
  const int dcol0 = dc * 128;

  const int tid = threadIdx.x;
  const int lane = tid & 63, wv = tid >> 6;
  const int lg = lane >> 4, ll = lane & 15;
  const int wm = wv >> 1, wn = wv & 1;

  const int sw = (tid * 16) ^ (((tid >> 3) & 7) << 4);
  const int srow = sw >> 6, scol = sw & 63;        // A: [0,256) via j*128+srow
  const int inner = (ll * 64 + lg * 16) ^ (((ll >> 1) & 7) << 4);

  const size_t pA = (size_t)W * 2;
  const size_t pB = (FULL ? (size_t)D_FF : (size_t)W) * 2;
  const char* gA = (const char*)(H + (size_t)grow0 * W) + (size_t)kc * KCH * 2;
  const char* gB = (const char*)(woP + ((size_t)e * D_MODEL + dcol0) * (pB / 2)
                                 + (FULL ? f0 : 0)) + (size_t)kc * KCH * 2;

  f32x4 acc[4][4];
  #pragma unroll
  for (int m = 0; m < 4; ++m)
    #pragma unroll
    for (int n = 0; n < 4; ++n) acc[m][n] = (f32x4){0.f, 0.f, 0.f, 0.f};

  // stage: A panel 256x64B (2 loads), B panel 128x64B (1 load, srow in [0,128))
  auto stage = [&](int kb, char* lbuf) {
    #pragma unroll
    for (int j = 0; j < 2; ++j)
      gload_lds16(gA + (size_t)(j * 128 + srow) * pA + kb + scol,
                  lbuf + j * 8192 + tid * 16);
    {
      int brow = srow & 127;   // sw>>6 for q=tid*16 within 8KB panel
      gload_lds16(gB + (size_t)brow * pB + kb + ((sw & 8191) & 63)
                  /* scol */, lbuf + 16384 + (tid & 511) * 16);
    }
  };
  // NOTE: B uses threads 0..511, 1 load each covering 8192B: row=(tid*16^swz)>>6
  // is identical to srow for tid<512 since panel is 8KB; guard via &127 removed:
  // srow in [0,256) for A-half j; for B we need q=tid*16 in [0,8192): tid<512 ok.

  const int NT = KCH / 32;
  stage(0, lds);
  stage(64, lds + BUF2);
  int bufi = 0;
  for (int t = 0; t < NT; ++t) {
    if (t < NT - 1) { asm volatile("s_waitcnt vmcnt(3)" ::: "memory"); }
    else            { asm volatile("s_waitcnt vmcnt(0)" ::: "memory"); }
    asm volatile("s_barrier" ::: "memory");
    const char* la = lds + bufi * BUF2 + wm * 4096;            // 64-row band
    const char* lb = lds + bufi * BUF2 + 16384 + wn * 4096;    // 64-col band
    if (t + 2 < NT) {
      int b2 = bufi + 2; if (b2 >= 3) b2 -= 3;
      stage((t + 2) * 64, lds + b2 * BUF2);
    }
    s16x8 bq0 = *(const s16x8*)(lb + 0 * 1024 + inner);
    s16x8 bq1 = *(const s16x8*)(lb + 1 * 1024 + inner);
    s16x8 bq2 = *(const s16x8*)(lb + 2 * 1024 + inner);
    s16x8 bq3 = *(const s16x8*)(lb + 3 * 1024 + inner);
    s16x8 a0 = *(const s16x8*)(la + 0 * 1024 + inner);
    s16x8 a1 = *(const s16x8*)(la + 1 * 1024 + inner);
    s16x8 a2 = *(const s16x8*)(la + 2 * 1024 + inner);
    s16x8 a3 = *(const s16x8*)(la + 3 * 1024 + inner);
    __builtin_amdgcn_s_setprio(1);
    acc[0][0] = __builtin_amdgcn_mfma_f32_16x16x32_bf16(a0, bq0, acc[0][0], 0, 0, 0);
    acc[0][1] = __builtin_amdgcn_mfma_f32_16x16x32_bf16(a0, bq1, acc[0][1], 0, 0, 0);
    acc[0][2] = __builtin_amdgcn_mfma_f32_16x16x32_bf16(a0, bq2, acc[0][2], 0, 0, 0);
    acc[0][3] = __builtin_amdgcn_mfma_f32_16x16x32_bf16(a0, bq3, acc[0][3], 0, 0, 0);
    acc[1][0] = __builtin_amdgcn_mfma_f32_16x16x32_bf16(a1, bq0, acc[1][0], 0, 0, 0);
    acc[1][1] = __builtin_amdgcn_mfma_f32_16x16x32_bf16(a1, bq1, acc[1][1], 0, 0, 0);
    acc[1][2] = __builtin_amdgcn_mfma_f32_16x16x32_bf16(a1, bq2, acc[1][2], 0, 0, 0);
    acc[1][3] = __builtin_amdgcn_mfma_f32_16x16x32_bf16(a1, bq3, acc[1][3], 0, 0, 0);
    acc[2][0] = __builtin_amdgcn_mfma_f32_16x16x32_bf16(a2, bq0, acc[2][0], 0, 0, 0);
    acc[2][1] = __builtin_amdgcn_mfma_f32_16x16x32_bf16(a2, bq1, acc[2][1], 0, 0, 0);
    acc[2][2] = __builtin_amdgcn_mfma_f32_16x16x32_bf16(a2, bq2, acc[2][2], 0, 0, 0);
    acc[2][3] = __builtin_amdgcn_mfma_f32_16x16x32_bf16(a2, bq3, acc[2][3], 0, 0, 0);
    acc[3][0] = __builtin_amdgcn_mfma_f32_16x16x32_bf16(a3, bq0, acc[3][0], 0, 0, 0);
    acc[3][1] = __builtin_amdgcn_mfma_f32_16x16x32_bf16(a3, bq1, acc[3][1], 0, 0, 0);
    acc[3][2] = __builtin_amdgcn_mfma_f32_16x16x32_bf16(a3, bq2, acc[3][2], 0, 0, 0);
    acc[3][3] = __builtin_amdgcn_mfma_f32_16x16x32_bf16(a3, bq3, acc[3][3], 0, 0, 0);
    __builtin_amdgcn_s_setprio(0);
    bufi += 1; if (bufi >= 3) bufi -= 3;
  }

  #pragma unroll
  for (int mf = 0; mf < 4; ++mf) {
    #pragma unroll
    for (int r = 0; r < 4; ++r) {
      int row = grow0 + wm * 64 + mf * 16 + lg * 4 + r;
      int tok = tokr[row];
      if (tok >= 0) {
        float w = wr[row];
        float* op = out + (size_t)tok * D_MODEL + dcol0 + wn * 64 + ll;
        #pragma unroll
        for (int nf = 0; nf < 4; ++nf)
          atomicAdd(op + nf * 16, acc[mf][nf][r] * w);
      }
    }
  }
}

// ---------------- host ----------------
extern "C" void kernel_launch(void* const* d_in, const int* in_sizes, int n_in,
                              void* d_out, int out_size, void* d_ws, size_t ws_size,
                              hipStream_t stream) {
  const float* hs  = (const float*)d_in[0];
  const int*   sel = (const int*)d_in[1];
  const float* rw  = (const float*)d_in[2];
  const float* wi  = (const float*)d_in[3];
  const float* wo  = (const float*)d_in[4];
  float* out = (float*)d_out;

  const size_t NW   = (size_t)NE * D_FF * D_MODEL;
  const size_t CTRL = 1u << 20;
  const size_t WB   = 2 * NW * sizeof(u16);
  const size_t XGB  = (size_t)ROWS_MAX * D_MODEL * 2;

  bool FULLW = true; int W = D_FF;
  {
    bool found = false;
    for (int f : {1, 2, 4, 8, 16}) {
      int Wc = D_FF / f;
      size_t need = CTRL + WB + XGB + (size_t)ROWS_MAX * Wc * 2;
      if (need <= ws_size) { FULLW = true; W = Wc; found = true; break; }
    }
    if (!found) {
      for (int Wc : {1024, 512, 256}) {
        size_t sl = (size_t)2 * NE * Wc * D_MODEL * 2;
        size_t need = CTRL + sl + XGB + (size_t)ROWS_MAX * Wc * 2;
        if (need <= ws_size) { FULLW = false; W = Wc; break; }
      }
    }
  }
  const int FS = D_FF / W;

  size_t off = 0;
  auto take = [&](size_t b) -> char* {
    char* r = (char*)d_ws + off; off = (off + b + 255) & ~(size_t)255; return r;
  };
  int*   tidx = (int*)take((size_t)NE * T_TOK * 4);
  float* tw   = (float*)take((size_t)NE * T_TOK * 4);
  int*   tokr = (int*)take((size_t)ROWS_MAX * 4);
  float* wrr  = (float*)take((size_t)ROWS_MAX * 4);
  int*   te2  = (int*)take(MT2 * 4);
  int*   cnt  = (int*)take(256);
  off = CTRL;
  u16 *wiP, *woP;
  if (FULLW) { wiP = (u16*)take(NW * 2); woP = (u16*)take(NW * 2); }
  else       { wiP = (u16*)take((size_t)NE * W * D_MODEL * 2);
               woP = (u16*)take((size_t)NE * D_MODEL * W * 2); }
  u16* Xg   = (u16*)take(XGB);
  u16* Hbuf = (u16*)take((size_t)ROWS_MAX * W * 2);

  hipMemsetAsync(cnt, 0, 256, stream);
  hipMemsetAsync(d_out, 0, (size_t)out_size * sizeof(float), stream);
  moe_route<<<T_TOK / 256, 256, 0, stream>>>(sel, rw, cnt, tidx, tw);
  moe_tilemap<<<64, 256, 0, stream>>>(cnt, tidx, tw, te2, tokr, wrr);
  moe_gather_x<<<ROWS_MAX, 256, 0, stream>>>(hs, tokr, Xg);
  if (FULLW)
    moe_cvt_w<<<(int)(2 * NW / 8 / 256), 256, 0, stream>>>(wi, wo, wiP, woP);

  hipFuncSetAttribute(reinterpret_cast<const void*>(&moe_g1<true>),
                      hipFuncAttributeMaxDynamicSharedMemorySize, LDS_G1);
  hipFuncSetAttribute(reinterpret_cast<const void*>(&moe_g1<false>),
                      hipFuncAttributeMaxDynamicSharedMemorySize, LDS_G1);
  hipFuncSetAttribute(reinterpret_cast<const void*>(&moe_g2<true>),
                      hipFuncAttributeMaxDynamicSharedMemorySize, LDS_G2);
  hipFuncSetAttribute(reinterpret_cast<const void*>(&moe_g2<false>),
                      hipFuncAttributeMaxDynamicSharedMemorySize, LDS_G2);

  const int KCH = W / 2;                              // kc in {0,1}
  const int g1grid = MT2 * (W / 256);                 // 1152 at FS=1
  const int g2grid = MT2 * 8 * 2;                     // 1152
  const int cvtblk = (int)(((size_t)NE * W * D_MODEL / 8) / 256);

  for (int p = 0; p < FS; ++p) {
    const int f0 = p * W;
    if (!FULLW) {
      moe_cvt_wi_s<<<cvtblk, 256, 0, stream>>>(wi, wiP, W, f0);
      moe_cvt_wo_s<<<cvtblk, 256, 0, stream>>>(wo, woP, W, f0);
    }
    if (FULLW) {
      moe_g1<true><<<g1grid, 512, LDS_G1, stream>>>(Xg, wiP, te2, Hbuf, W, f0);
      moe_g2<true><<<g2grid, 512, LDS_G2, stream>>>(Hbuf, woP, te2, tokr, wrr,
                                                    out, W, f0, KCH);
    } else {
      moe_g1<false><<<g1grid, 512, LDS_G1, stream>>>(Xg, wiP, te2, Hbuf, W, f0);
      moe_g2<false><<<g2grid, 512, LDS_G2, stream>>>(Hbuf, woP, te2, tokr, wrr,
                                                     out, W, f0, KCH);
    }
  }
}

// Round 12
// 523.622 us; speedup vs baseline: 1.2668x; 1.0258x over previous
//
#include <hip/hip_runtime.h>
#include <hip/hip_bf16.h>

// MoE Experts v12: v11 with the K-loop de-lockstepped (both GEMMs):
// - mid-iteration s_barrier removed (no data role; waves now phase-skew,
//   giving setprio role diversity: T5 prerequisite)
// - stage split per phase (g1 2+2, g2 2+1 loads) issued between ds_reads and
//   MFMA cluster; boundary vmcnt(4)/vmcnt(3) unchanged.
// g1: 256x256, 3x32KB bufs. g2: 256x128, 3x24KB bufs, 2 blocks/CU.

#define T_TOK   8192
#define D_MODEL 1024
#define D_FF    4096
#define NE      8
#define MT2     72                 // 256-row tiles
#define ROWS_MAX (MT2 * 256)       // 18432
#define BUFB    32768              // g1 buffer stride (A16K+B16K)
#define LDS_G1  98304
#define BUF2    24576              // g2 buffer stride (A16K+B8K)
#define LDS_G2  73728

typedef float f32x4 __attribute__((ext_vector_type(4)));
typedef short s16x8 __attribute__((ext_vector_type(8)));
typedef short s16x4 __attribute__((ext_vector_type(4)));
typedef unsigned short u16;

__device__ __forceinline__ u16 f2bf(float x) {
  __hip_bfloat16 h = __float2bfloat16(x);   // RNE
  return *reinterpret_cast<u16*>(&h);
}

__device__ __forceinline__ s16x8 cvt8(float4 a, float4 b) {
  s16x8 v;
  v[0] = (short)f2bf(a.x); v[1] = (short)f2bf(a.y);
  v[2] = (short)f2bf(a.z); v[3] = (short)f2bf(a.w);
  v[4] = (short)f2bf(b.x); v[5] = (short)f2bf(b.y);
  v[6] = (short)f2bf(b.z); v[7] = (short)f2bf(b.w);
  return v;
}

__device__ __forceinline__ void gload_lds16(const void* g, void* l) {
  __builtin_amdgcn_global_load_lds((const __attribute__((address_space(1))) void*)g,
                                   (__attribute__((address_space(3))) void*)l,
                                   16, 0, 0);
}

// ---------------- routing compaction ----------------
__global__ void moe_route(const int* __restrict__ sel, const float* __restrict__ rw,
                          int* __restrict__ cnt, int* __restrict__ tidx,
                          float* __restrict__ tw) {
  int t = blockIdx.x * blockDim.x + threadIdx.x;
  if (t >= T_TOK) return;
  int e0 = 0, e1 = 0;
  #pragma unroll
  for (int e = 0; e < NE; ++e) {
    if (sel[t * 16 + e])     e0 = e;
    if (sel[t * 16 + 8 + e]) e1 = e;
  }
  float w0 = rw[2 * t], w1 = rw[2 * t + 1];
  if (e0 == e1) {
    int p = atomicAdd(&cnt[e0], 1);
    tidx[e0 * T_TOK + p] = t; tw[e0 * T_TOK + p] = w0 + w1;
  } else {
    int p = atomicAdd(&cnt[e0], 1);
    tidx[e0 * T_TOK + p] = t; tw[e0 * T_TOK + p] = w0;
    int q = atomicAdd(&cnt[e1], 1);
    tidx[e1 * T_TOK + q] = t; tw[e1 * T_TOK + q] = w1;
  }
}

// ---------------- tile map: 256-aligned per-expert segments ----------------
__global__ void moe_tilemap(const int* __restrict__ cnt, const int* __restrict__ tidx,
                            const float* __restrict__ tw, int* __restrict__ te256,
                            int* __restrict__ tokr, float* __restrict__ wr) {
  int off[NE + 1];
  {
    int o = 0;
    #pragma unroll
    for (int e = 0; e < NE; ++e) { off[e] = o; o += (cnt[e] + 255) & ~255; }
    off[NE] = o;
  }
  const int total = off[NE];
  const int gid = blockIdx.x * blockDim.x + threadIdx.x;
  const int stride = gridDim.x * blockDim.x;
  for (int t = gid; t < MT2; t += stride) {
    int r0 = t * 256; int e = -1;
    if (r0 < total) {
      #pragma unroll
      for (int i = NE - 1; i >= 0; --i) if (r0 >= off[i]) { e = i; break; }
    }
    te256[t] = e;
  }
  for (int i = gid; i < ROWS_MAX; i += stride) {
    if (i >= total) { tokr[i] = -1; wr[i] = 0.f; continue; }
    int e = 0;
    #pragma unroll
    for (int k = NE - 1; k >= 0; --k) if (i >= off[k]) { e = k; break; }
    int j = i - off[e];
    int ok = j < cnt[e];
    tokr[i] = ok ? tidx[e * T_TOK + j] : -1;
    wr[i]   = ok ? tw[e * T_TOK + j] : 0.f;
  }
}

// ---------------- gather X rows -> bf16 Xg ----------------
__global__ void moe_gather_x(const float* __restrict__ hs, const int* __restrict__ tokr,
                             u16* __restrict__ Xg) {
  int row = blockIdx.x;
  int tok = tokr[row];
  int c = threadIdx.x * 4;
  u16* dst = Xg + (size_t)row * D_MODEL + c;
  s16x4 o;
  if (tok < 0) {
    o[0] = o[1] = o[2] = o[3] = 0;
  } else {
    float4 v = *(const float4*)(hs + (size_t)tok * D_MODEL + c);
    o[0] = (short)f2bf(v.x); o[1] = (short)f2bf(v.y);
    o[2] = (short)f2bf(v.z); o[3] = (short)f2bf(v.w);
  }
  *(s16x4*)dst = o;
}

// ---------------- f32 -> bf16 weight converts ----------------
__global__ void moe_cvt_w(const float* __restrict__ wi, const float* __restrict__ wo,
                          u16* __restrict__ wib, u16* __restrict__ wob) {
  const size_t NW = (size_t)NE * D_FF * D_MODEL;
  size_t i = ((size_t)blockIdx.x * blockDim.x + threadIdx.x) * 8;
  const float* src; u16* dst;
  if (i < NW) { src = wi + i; dst = wib + i; }
  else        { src = wo + (i - NW); dst = wob + (i - NW); }
  float4 a = *(const float4*)(src);
  float4 b = *(const float4*)(src + 4);
  *(s16x8*)dst = cvt8(a, b);
}

__global__ void moe_cvt_wi_s(const float* __restrict__ wi, u16* __restrict__ wis,
                             int W, int f0) {
  size_t i = ((size_t)blockIdx.x * blockDim.x + threadIdx.x) * 8;
  size_t per = (size_t)W * D_MODEL;
  int e = (int)(i / per); size_t r = i % per;
  const float* src = wi + ((size_t)e * D_FF + f0) * D_MODEL + r;
  float4 a = *(const float4*)src;
  float4 b = *(const float4*)(src + 4);
  *(s16x8*)(wis + i) = cvt8(a, b);
}

__global__ void moe_cvt_wo_s(const float* __restrict__ wo, u16* __restrict__ wos,
                             int W, int f0) {
  size_t i = ((size_t)blockIdx.x * blockDim.x + threadIdx.x) * 8;
  size_t per = (size_t)D_MODEL * W;
  int e = (int)(i / per); size_t r = i % per;
  int row = (int)(r / W), col = (int)(r % W);
  const float* src = wo + ((size_t)e * D_MODEL + row) * D_FF + f0 + col;
  float4 a = *(const float4*)src;
  float4 b = *(const float4*)(src + 4);
  *(s16x8*)(wos + i) = cvt8(a, b);
}

// ---------------- GEMM1: 256x256 deep-pipe, de-lockstepped ----------------
template <bool FULL>
__global__ __launch_bounds__(512, 1)
void moe_g1(const u16* __restrict__ Xg, const u16* __restrict__ wiP,
            const int* __restrict__ te256, u16* __restrict__ H,
            int W, int f0) {
  extern __shared__ char lds[];
  const int GR = gridDim.x;
  const int task = (blockIdx.x & 7) * (GR >> 3) + (blockIdx.x >> 3);
  const int mt = task % MT2;
  const int nc = task / MT2;
  const int e = te256[mt];
  if (e < 0) return;
  const int grow0 = mt * 256;
  const int fcol = nc * 256;

  const int tid = threadIdx.x;
  const int lane = tid & 63, wv = tid >> 6;
  const int lg = lane >> 4, ll = lane & 15;
  const int wm = wv >> 2, wn = wv & 3;

  const int sw = (tid * 16) ^ (((tid >> 3) & 7) << 4);
  const int srow = sw >> 6, scol = sw & 63;
  const int inner = (ll * 64 + lg * 16) ^ (((ll >> 1) & 7) << 4);

  const char* gA = (const char*)(Xg + (size_t)grow0 * D_MODEL);
  const char* gB = (const char*)(wiP + (FULL ? ((size_t)e * D_FF + f0 + fcol)
                                             : ((size_t)e * W + fcol)) * D_MODEL);

  f32x4 acc[8][4];
  #pragma unroll
  for (int m = 0; m < 8; ++m)
    #pragma unroll
    for (int n = 0; n < 4; ++n) acc[m][n] = (f32x4){0.f, 0.f, 0.f, 0.f};

  auto stageA = [&](int kb, char* lbuf) {
    #pragma unroll
    for (int j = 0; j < 2; ++j)
      gload_lds16(gA + (size_t)(j * 128 + srow) * 2048 + kb + scol,
                  lbuf + j * 8192 + tid * 16);
  };
  auto stageB = [&](int kb, char* lbuf) {
    #pragma unroll
    for (int j = 0; j < 2; ++j)
      gload_lds16(gB + (size_t)(j * 128 + srow) * 2048 + kb + scol,
                  lbuf + 16384 + j * 8192 + tid * 16);
  };

  const int NT = D_MODEL / 32;                 // 32 K-tiles of BK=32
  stageA(0, lds);   stageB(0, lds);
  stageA(64, lds + BUFB); stageB(64, lds + BUFB);
  int bufi = 0;
  for (int t = 0; t < NT; ++t) {
    if (t < NT - 1) { asm volatile("s_waitcnt vmcnt(4)" ::: "memory"); }
    else            { asm volatile("s_waitcnt vmcnt(0)" ::: "memory"); }
    asm volatile("s_barrier" ::: "memory");
    const char* la = lds + bufi * BUFB + wm * 8192;
    const char* lb = lds + bufi * BUFB + 16384 + wn * 4096;
    int b2 = bufi + 2; if (b2 >= 3) b2 -= 3;
    const bool pf = (t + 2 < NT);
    // ---- phase 1: B frags + A frags 0..3, stage A-half, 16 MFMA ----
    s16x8 bq0 = *(const s16x8*)(lb + 0 * 1024 + inner);
    s16x8 bq1 = *(const s16x8*)(lb + 1 * 1024 + inner);
    s16x8 bq2 = *(const s16x8*)(lb + 2 * 1024 + inner);
    s16x8 bq3 = *(const s16x8*)(lb + 3 * 1024 + inner);
    {
      s16x8 a0 = *(const s16x8*)(la + 0 * 1024 + inner);
      s16x8 a1 = *(const s16x8*)(la + 1 * 1024 + inner);
      s16x8 a2 = *(const s16x8*)(la + 2 * 1024 + inner);
      s16x8 a3 = *(const s16x8*)(la + 3 * 1024 + inner);
      if (pf) stageA((t + 2) * 64, lds + b2 * BUFB);
      __builtin_amdgcn_s_setprio(1);
      acc[0][0] = __builtin_amdgcn_mfma_f32_16x16x32_bf16(a0, bq0, acc[0][0], 0, 0, 0);
      acc[0][1] = __builtin_amdgcn_mfma_f32_16x16x32_bf16(a0, bq1, acc[0][1], 0, 0, 0);
      acc[0][2] = __builtin_amdgcn_mfma_f32_16x16x32_bf16(a0, bq2, acc[0][2], 0, 0, 0);
      acc[0][3] = __builtin_amdgcn_mfma_f32_16x16x32_bf16(a0, bq3, acc[0][3], 0, 0, 0);
      acc[1][0] = __builtin_amdgcn_mfma_f32_16x16x32_bf16(a1, bq0, acc[1][0], 0, 0, 0);
      acc[1][1] = __builtin_amdgcn_mfma_f32_16x16x32_bf16(a1, bq1, acc[1][1], 0, 0, 0);
      acc[1][2] = __builtin_amdgcn_mfma_f32_16x16x32_bf16(a1, bq2, acc[1][2], 0, 0, 0);
      acc[1][3] = __builtin_amdgcn_mfma_f32_16x16x32_bf16(a1, bq3, acc[1][3], 0, 0, 0);
      acc[2][0] = __builtin_amdgcn_mfma_f32_16x16x32_bf16(a2, bq0, acc[2][0], 0, 0, 0);
      acc[2][1] = __builtin_amdgcn_mfma_f32_16x16x32_bf16(a2, bq1, acc[2][1], 0, 0, 0);
      acc[2][2] = __builtin_amdgcn_mfma_f32_16x16x32_bf16(a2, bq2, acc[2][2], 0, 0, 0);
      acc[2][3] = __builtin_amdgcn_mfma_f32_16x16x32_bf16(a2, bq3, acc[2][3], 0, 0, 0);
      acc[3][0] = __builtin_amdgcn_mfma_f32_16x16x32_bf16(a3, bq0, acc[3][0], 0, 0, 0);
      acc[3][1] = __builtin_amdgcn_mfma_f32_16x16x32_bf16(a3, bq1, acc[3][1], 0, 0, 0);
      acc[3][2] = __builtin_amdgcn_mfma_f32_16x16x32_bf16(a3, bq2, acc[3][2], 0, 0, 0);
      acc[3][3] = __builtin_amdgcn_mfma_f32_16x16x32_bf16(a3, bq3, acc[3][3], 0, 0, 0);
      __builtin_amdgcn_s_setprio(0);
    }
    // ---- phase 2: A frags 4..7, stage B-half, 16 MFMA (no mid barrier) ----
    {
      s16x8 a0 = *(const s16x8*)(la + 4 * 1024 + inner);
      s16x8 a1 = *(const s16x8*)(la + 5 * 1024 + inner);
      s16x8 a2 = *(const s16x8*)(la + 6 * 1024 + inner);
      s16x8 a3 = *(const s16x8*)(la + 7 * 1024 + inner);
      if (pf) stageB((t + 2) * 64, lds + b2 * BUFB);
      __builtin_amdgcn_s_setprio(1);
      acc[4][0] = __builtin_amdgcn_mfma_f32_16x16x32_bf16(a0, bq0, acc[4][0], 0, 0, 0);
      acc[4][1] = __builtin_amdgcn_mfma_f32_16x16x32_bf16(a0, bq1, acc[4][1], 0, 0, 0);
      acc[4][2] = __builtin_amdgcn_mfma_f32_16x16x32_bf16(a0, bq2, acc[4][2], 0, 0, 0);
      acc[4][3] = __builtin_amdgcn_mfma_f32_16x16x32_bf16(a0, bq3, acc[4][3], 0, 0, 0);
      acc[5][0] = __builtin_amdgcn_mfma_f32_16x16x32_bf16(a1, bq0, acc[5][0], 0, 0, 0);
      acc[5][1] = __builtin_amdgcn_mfma_f32_16x16x32_bf16(a1, bq1, acc[5][1], 0, 0, 0);
      acc[5][2] = __builtin_amdgcn_mfma_f32_16x16x32_bf16(a1, bq2, acc[5][2], 0, 0, 0);
      acc[5][3] = __builtin_amdgcn_mfma_f32_16x16x32_bf16(a1, bq3, acc[5][3], 0, 0, 0);
      acc[6][0] = __builtin_amdgcn_mfma_f32_16x16x32_bf16(a2, bq0, acc[6][0], 0, 0, 0);
      acc[6][1] = __builtin_amdgcn_mfma_f32_16x16x32_bf16(a2, bq1, acc[6][1], 0, 0, 0);
      acc[6][2] = __builtin_amdgcn_mfma_f32_16x16x32_bf16(a2, bq2, acc[6][2], 0, 0, 0);
      acc[6][3] = __builtin_amdgcn_mfma_f32_16x16x32_bf16(a2, bq3, acc[6][3], 0, 0, 0);
      acc[7][0] = __builtin_amdgcn_mfma_f32_16x16x32_bf16(a3, bq0, acc[7][0], 0, 0, 0);
      acc[7][1] = __builtin_amdgcn_mfma_f32_16x16x32_bf16(a3, bq1, acc[7][1], 0, 0, 0);
      acc[7][2] = __builtin_amdgcn_mfma_f32_16x16x32_bf16(a3, bq2, acc[7][2], 0, 0, 0);
      acc[7][3] = __builtin_amdgcn_mfma_f32_16x16x32_bf16(a3, bq3, acc[7][3], 0, 0, 0);
      __builtin_amdgcn_s_setprio(0);
    }
    bufi += 1; if (bufi >= 3) bufi -= 3;
  }

  #pragma unroll
  for (int mf = 0; mf < 8; ++mf) {
    #pragma unroll
    for (int r = 0; r < 4; ++r) {
      int row = grow0 + wm * 128 + mf * 16 + lg * 4 + r;
      u16* hp = H + (size_t)row * W + fcol + wn * 64 + ll;
      #pragma unroll
      for (int nf = 0; nf < 4; ++nf) {
        float v = acc[mf][nf][r];
        hp[nf * 16] = f2bf(v > 0.f ? v : 0.f);
      }
    }
  }
}

// ---------------- GEMM2: 256x128 deep-pipe, de-lockstepped ----------------
template <bool FULL>
__global__ __launch_bounds__(512, 4)
void moe_g2(const u16* __restrict__ H, const u16* __restrict__ woP,
            const int* __restrict__ te256, const int* __restrict__ tokr,
            const float* __restrict__ wr, float* __restrict__ out,
            int W, int f0, int KCH) {
  extern __shared__ char lds[];
  const int GR = gridDim.x;
  const int task = (blockIdx.x & 7) * (GR >> 3) + (blockIdx.x >> 3);
  const int dc = task & 7;
  const int rest = task >> 3;
  const int mt = rest % MT2;
  const int kc = rest / MT2;
  const int e = te256[mt];
  if (e < 0) return;
  const int grow0 = mt * 256;
  const int dcol0 = dc * 128;

  const int tid = threadIdx.x;
  const int lane = tid & 63, wv = tid >> 6;
  const int lg = lane >> 4, ll = lane & 15;
  const int wm = wv >> 1, wn = wv & 1;

  const int sw = (tid * 16) ^ (((tid >> 3) & 7) << 4);
  const int srow = sw >> 6, scol = sw & 63;
  const int inner = (ll * 64 + lg * 16) ^ (((ll >> 1) & 7) << 4);

  const size_t pA = (size_t)W * 2;
  const size_t pB = (FULL ? (size_t)D_FF : (size_t)W) * 2;
  const char* gA = (const char*)(H + (size_t)grow0 * W) + (size_t)kc * KCH * 2;
  const char* gB = (const char*)(woP + ((size_t)e * D_MODEL + dcol0) * (pB / 2)
                                 + (FULL ? f0 : 0)) + (size_t)kc * KCH * 2;

  f32x4 acc[4][4];
  #pragma unroll
  for (int m = 0; m < 4; ++m)
    #pragma unroll
    for (int n = 0; n < 4; ++n) acc[m][n] = (f32x4){0.f, 0.f, 0.f, 0.f};

  auto stageA = [&](int kb, char* lbuf) {
    #pragma unroll
    for (int j = 0; j < 2; ++j)
      gload_lds16(gA + (size_t)(j * 128 + srow) * pA + kb + scol,
                  lbuf + j * 8192 + tid * 16);
  };
  auto stageB = [&](int kb, char* lbuf) {
    gload_lds16(gB + (size_t)srow * pB + kb + scol, lbuf + 16384 + tid * 16);
  };

  const int NT = KCH / 32;
  stageA(0, lds);   stageB(0, lds);
  stageA(64, lds + BUF2); stageB(64, lds + BUF2);
  int bufi = 0;
  for (int t = 0; t < NT; ++t) {
    if (t < NT - 1) { asm volatile("s_waitcnt vmcnt(3)" ::: "memory"); }
    else            { asm volatile("s_waitcnt vmcnt(0)" ::: "memory"); }
    asm volatile("s_barrier" ::: "memory");
    const char* la = lds + bufi * BUF2 + wm * 4096;
    const char* lb = lds + bufi * BUF2 + 16384 + wn * 4096;
    int b2 = bufi + 2; if (b2 >= 3) b2 -= 3;
    const bool pf = (t + 2 < NT);
    // phase 1: B frags + A frags 0..1, stage A-half, 8 MFMA
    s16x8 bq0 = *(const s16x8*)(lb + 0 * 1024 + inner);
    s16x8 bq1 = *(const s16x8*)(lb + 1 * 1024 + inner);
    s16x8 bq2 = *(const s16x8*)(lb + 2 * 1024 + inner);
    s16x8 bq3 = *(const s16x8*)(lb + 3 * 1024 + inner);
    {
      s16x8 a0 = *(const s16x8*)(la + 0 * 1024 + inner);
      s16x8 a1 = *(const s16x8*)(la + 1 * 1024 + inner);
      if (pf) stageA((t + 2) * 64, lds + b2 * BUF2);
      __builtin_amdgcn_s_setprio(1);
      acc[0][0] = __builtin_amdgcn_mfma_f32_16x16x32_bf16(a0, bq0, acc[0][0], 0, 0, 0);
      acc[0][1] = __builtin_amdgcn_mfma_f32_16x16x32_bf16(a0, bq1, acc[0][1], 0, 0, 0);
      acc[0][2] = __builtin_amdgcn_mfma_f32_16x16x32_bf16(a0, bq2, acc[0][2], 0, 0, 0);
      acc[0][3] = __builtin_amdgcn_mfma_f32_16x16x32_bf16(a0, bq3, acc[0][3], 0, 0, 0);
      acc[1][0] = __builtin_amdgcn_mfma_f32_16x16x32_bf16(a1, bq0, acc[1][0], 0, 0, 0);
      acc[1][1] = __builtin_amdgcn_mfma_f32_16x16x32_bf16(a1, bq1, acc[1][1], 0, 0, 0);
      acc[1][2] = __builtin_amdgcn_mfma_f32_16x16x32_bf16(a1, bq2, acc[1][2], 0, 0, 0);
      acc[1][3] = __builtin_amdgcn_mfma_f32_16x16x32_bf16(a1, bq3, acc[1][3], 0, 0, 0);
      __builtin_amdgcn_s_setprio(0);
    }
    // phase 2: A frags 2..3, stage B-half, 8 MFMA (no mid barrier)
    {
      s16x8 a2 = *(const s16x8*)(la + 2 * 1024 + inner);
      s16x8 a3 = *(const s16x8*)(la + 3 * 1024 + inner);
      if (pf) stageB((t + 2) * 64, lds + b2 * BUF2);
      __builtin_amdgcn_s_setprio(1);
      acc[2][0] = __builtin_amdgcn_mfma_f32_16x16x32_bf16(a2, bq0, acc[2][0], 0, 0, 0);
      acc[2][1] = __builtin_amdgcn_mfma_f32_16x16x32_bf16(a2, bq1, acc[2][1], 0, 0, 0);
      acc[2][2] = __builtin_amdgcn_mfma_f32_16x16x32_bf16(a2, bq2, acc[2][2], 0, 0, 0);
      acc[2][3] = __builtin_amdgcn_mfma_f32_16x16x32_bf16(a2, bq3, acc[2][3], 0, 0, 0);
      acc[3][0] = __builtin_amdgcn_mfma_f32_16x16x32_bf16(a3, bq0, acc[3][0], 0, 0, 0);
      acc[3][1] = __builtin_amdgcn_mfma_f32_16x16x32_bf16(a3, bq1, acc[3][1], 0, 0, 0);
      acc[3][2] = __builtin_amdgcn_mfma_f32_16x16x32_bf16(a3, bq2, acc[3][2], 0, 0, 0);
      acc[3][3] = __builtin_amdgcn_mfma_f32_16x16x32_bf16(a3, bq3, acc[3][3], 0, 0, 0);
      __builtin_amdgcn_s_setprio(0);
    }
    bufi += 1; if (bufi >= 3) bufi -= 3;
  }

  #pragma unroll
  for (int mf = 0; mf < 4; ++mf) {
    #pragma unroll
    for (int r = 0; r < 4; ++r) {
      int row = grow0 + wm * 64 + mf * 16 + lg * 4 + r;
      int tok = tokr[row];
      if (tok >= 0) {
        float w = wr[row];
        float* op = out + (size_t)tok * D_MODEL + dcol0 + wn * 64 + ll;
        #pragma unroll
        for (int nf = 0; nf < 4; ++nf)
          atomicAdd(op + nf * 16, acc[mf][nf][r] * w);
      }
    }
  }
}

// ---------------- host ----------------
extern "C" void kernel_launch(void* const* d_in, const int* in_sizes, int n_in,
                              void* d_out, int out_size, void* d_ws, size_t ws_size,
                              hipStream_t stream) {
  const float* hs  = (const float*)d_in[0];
  const int*   sel = (const int*)d_in[1];
  const float* rw  = (const float*)d_in[2];
  const float* wi  = (const float*)d_in[3];
  const float* wo  = (const float*)d_in[4];
  float* out = (float*)d_out;

  const size_t NW   = (size_t)NE * D_FF * D_MODEL;
  const size_t CTRL = 1u << 20;
  const size_t WB   = 2 * NW * sizeof(u16);
  const size_t XGB  = (size_t)ROWS_MAX * D_MODEL * 2;

  bool FULLW = true; int W = D_FF;
  {
    bool found = false;
    for (int f : {1, 2, 4, 8, 16}) {
      int Wc = D_FF / f;
      size_t need = CTRL + WB + XGB + (size_t)ROWS_MAX * Wc * 2;
      if (need <= ws_size) { FULLW = true; W = Wc; found = true; break; }
    }
    if (!found) {
      for (int Wc : {1024, 512, 256}) {
        size_t sl = (size_t)2 * NE * Wc * D_MODEL * 2;
        size_t need = CTRL + sl + XGB + (size_t)ROWS_MAX * Wc * 2;
        if (need <= ws_size) { FULLW = false; W = Wc; break; }
      }
    }
  }
  const int FS = D_FF / W;

  size_t off = 0;
  auto take = [&](size_t b) -> char* {
    char* r = (char*)d_ws + off; off = (off + b + 255) & ~(size_t)255; return r;
  };
  int*   tidx = (int*)take((size_t)NE * T_TOK * 4);
  float* tw   = (float*)take((size_t)NE * T_TOK * 4);
  int*   tokr = (int*)take((size_t)ROWS_MAX * 4);
  float* wrr  = (float*)take((size_t)ROWS_MAX * 4);
  int*   te2  = (int*)take(MT2 * 4);
  int*   cnt  = (int*)take(256);
  off = CTRL;
  u16 *wiP, *woP;
  if (FULLW) { wiP = (u16*)take(NW * 2); woP = (u16*)take(NW * 2); }
  else       { wiP = (u16*)take((size_t)NE * W * D_MODEL * 2);
               woP = (u16*)take((size_t)NE * D_MODEL * W * 2); }
  u16* Xg   = (u16*)take(XGB);
  u16* Hbuf = (u16*)take((size_t)ROWS_MAX * W * 2);

  hipMemsetAsync(cnt, 0, 256, stream);
  hipMemsetAsync(d_out, 0, (size_t)out_size * sizeof(float), stream);
  moe_route<<<T_TOK / 256, 256, 0, stream>>>(sel, rw, cnt, tidx, tw);
  moe_tilemap<<<64, 256, 0, stream>>>(cnt, tidx, tw, te2, tokr, wrr);
  moe_gather_x<<<ROWS_MAX, 256, 0, stream>>>(hs, tokr, Xg);
  if (FULLW)
    moe_cvt_w<<<(int)(2 * NW / 8 / 256), 256, 0, stream>>>(wi, wo, wiP, woP);

  hipFuncSetAttribute(reinterpret_cast<const void*>(&moe_g1<true>),
                      hipFuncAttributeMaxDynamicSharedMemorySize, LDS_G1);
  hipFuncSetAttribute(reinterpret_cast<const void*>(&moe_g1<false>),
                      hipFuncAttributeMaxDynamicSharedMemorySize, LDS_G1);
  hipFuncSetAttribute(reinterpret_cast<const void*>(&moe_g2<true>),
                      hipFuncAttributeMaxDynamicSharedMemorySize, LDS_G2);
  hipFuncSetAttribute(reinterpret_cast<const void*>(&moe_g2<false>),
                      hipFuncAttributeMaxDynamicSharedMemorySize, LDS_G2);

  const int KCH = W / 2;
  const int g1grid = MT2 * (W / 256);
  const int g2grid = MT2 * 8 * 2;
  const int cvtblk = (int)(((size_t)NE * W * D_MODEL / 8) / 256);

  for (int p = 0; p < FS; ++p) {
    const int f0 = p * W;
    if (!FULLW) {
      moe_cvt_wi_s<<<cvtblk, 256, 0, stream>>>(wi, wiP, W, f0);
      moe_cvt_wo_s<<<cvtblk, 256, 0, stream>>>(wo, woP, W, f0);
    }
    if (FULLW) {
      moe_g1<true><<<g1grid, 512, LDS_G1, stream>>>(Xg, wiP, te2, Hbuf, W, f0);
      moe_g2<true><<<g2grid, 512, LDS_G2, stream>>>(Hbuf, woP, te2, tokr, wrr,
                                                    out, W, f0, KCH);
    } else {
      moe_g1<false><<<g1grid, 512, LDS_G1, stream>>>(Xg, wiP, te2, Hbuf, W, f0);
      moe_g2<false><<<g2grid, 512, LDS_G2, stream>>>(Hbuf, woP, te2, tokr, wrr,
                                                     out, W, f0, KCH);
    }
  }
}